// Round 4
// baseline (225.558 us; speedup 1.0000x reference)
//
#include <hip/hip_runtime.h>

#define EPS 1e-5f
#define LOG2E 1.4426950408889634f

typedef float f32x4 __attribute__((ext_vector_type(4)));

// ---------------------------------------------------------------------------
// Persistent fused kernel: 256 blocks x 1024 threads, one block per CU, each
// block processes TWO (b,c) channels back-to-back.
// Per channel: 16 waves x 64 lanes x 16 float4 = the full 256x256 channel in
// registers. Wave w owns the 64x64 patch (pr=w>>2, pc=w&3).
//   Phase 1: nt-load channel (x is read exactly once -> nt keeps caches clean).
//   Phase 2: shfl-reduce -> per-patch sum/sumsq in LDS.
//   Phase 3: threads 0..20 fold stats into exp2-ready coefs for p=2/1/0.
//   Phase 4: apply 3 sigmoids + store; for ch0 the it-th slot of the NEXT
//            channel is nt-loaded BEFORE the slot's store is issued.
// Stores are PLAIN (not nt): vmcnt-ack happens at L2 (~200cy) instead of HBM
// (~900cy+drain), so the ch1 reduction - whose s_waitcnt necessarily covers
// the interleaved older stores (vmcnt is an ordered counter) - no longer
// serializes behind ch0's 256 KB/CU store drain. L2 write-back streams the
// output to HBM asynchronously under ch1's compute. Same at kernel end.
// HBM traffic = 134 MB read + 134 MB write = floor (~43 us at ~6.3 TB/s).
// ---------------------------------------------------------------------------
__global__ __launch_bounds__(1024) void k_fused(const f32x4* __restrict__ x4,
                                                const float* __restrict__ lw,
                                                f32x4* __restrict__ out4) {
    const int t    = threadIdx.x;
    const int w    = t >> 6, lane = t & 63;
    const int pr   = w >> 2, pc = w & 3;
    // row = pr*64 + it*4 + (lane>>4), col4 = pc*16 + (lane&15): each wave load
    // is 4 rows x 256 B contiguous segments, fully coalesced.
    const int off0 = (pr * 64 + (lane >> 4)) * 64 + pc * 16 + (lane & 15);

    // Softmaxed level weights (wave-uniform -> scalar loads / SGPR math).
    const float w0 = lw[0], w1 = lw[1], w2 = lw[2];
    const float mx = fmaxf(w0, fmaxf(w1, w2));
    const float a0 = __expf(w0 - mx), a1 = __expf(w1 - mx), a2 = __expf(w2 - mx);
    const float ainv = 1.f / (a0 + a1 + a2);
    const float lwA = a0 * ainv;   // pairs with p=2 (64x64)
    const float lwB = a1 * ainv;   // pairs with p=1 (128x128)
    const float lwC = a2 * ainv;   // pairs with p=0 (full)

    __shared__ float2 ps[16];      // per-patch (sum, sumsq)
    __shared__ float2 coefs[21];   // 16 x p=2, 4 x p=1, 1 x p=0

    long base = (((long)blockIdx.x * 2) << 14) + off0;

    f32x4 d[16];
#pragma unroll
    for (int it = 0; it < 16; ++it)
        d[it] = __builtin_nontemporal_load(x4 + base + it * 256);

#pragma unroll
    for (int ch = 0; ch < 2; ++ch) {
        float s = 0.f, ss = 0.f;
#pragma unroll
        for (int it = 0; it < 16; ++it) {
            const f32x4 v = d[it];
            s  += v[0] + v[1] + v[2] + v[3];
            ss += v[0] * v[0] + v[1] * v[1] + v[2] * v[2] + v[3] * v[3];
        }
#pragma unroll
        for (int off = 32; off > 0; off >>= 1) {
            s  += __shfl_down(s, off, 64);
            ss += __shfl_down(ss, off, 64);
        }
        if (lane == 0) ps[w] = make_float2(s, ss);
        __syncthreads();

        if (t < 21) {
            float sum = 0.f, sq = 0.f, n;
            if (t < 16) {                    // p=2: one 64x64 patch
                sum = ps[t].x; sq = ps[t].y; n = 4096.f;
            } else if (t < 20) {             // p=1: 2x2 patch group (128x128)
                const int g = t - 16, gr = g >> 1, gc = g & 1;
                const int b = 8 * gr + 2 * gc;
                sum = ps[b].x + ps[b + 1].x + ps[b + 4].x + ps[b + 5].x;
                sq  = ps[b].y + ps[b + 1].y + ps[b + 4].y + ps[b + 5].y;
                n = 16384.f;
            } else {                         // p=0: full channel
#pragma unroll
                for (int i = 0; i < 16; ++i) { sum += ps[i].x; sq += ps[i].y; }
                n = 65536.f;
            }
            const float mu   = sum / n;
            const float var  = sq / n - mu * mu;
            const float rstd = rsqrtf(var + EPS);
            coefs[t] = make_float2(-rstd * LOG2E, mu * rstd * LOG2E);
        }
        __syncthreads();

        // All three coef pairs are wave-uniform.
        const float2 c2 = coefs[w];
        const float2 c1 = coefs[16 + (pr >> 1) * 2 + (pc >> 1)];
        const float2 c0 = coefs[20];
        const long nbase = base + 16384;   // next channel of this block

#pragma unroll
        for (int it = 0; it < 16; ++it) {
            const f32x4 v = d[it];
            if (ch == 0)   // prefetch next channel; load issued BEFORE store
                d[it] = __builtin_nontemporal_load(x4 + nbase + it * 256);
            f32x4 r;
#pragma unroll
            for (int j = 0; j < 4; ++j) {
                const float xv = v[j];
                const float e2 = __builtin_amdgcn_exp2f(fmaf(xv, c2.x, c2.y));
                const float e1 = __builtin_amdgcn_exp2f(fmaf(xv, c1.x, c1.y));
                const float e0 = __builtin_amdgcn_exp2f(fmaf(xv, c0.x, c0.y));
                const float pA = 1.f + e2, pB = 1.f + e1, pC = 1.f + e0;
                const float mBC = pB * pC, mAB = pA * pB, mAC = pA * pC;
                const float num = fmaf(lwA, mBC, fmaf(lwB, mAC, lwC * mAB));
                const float den = mAB * pC;
                const float t0  = 0.5f * xv;
                r[j] = fmaf(t0 * num, __builtin_amdgcn_rcpf(den), t0);
            }
            out4[base + it * 256] = r;   // plain store: acks at L2, drains async
        }
        base = nbase;
    }
}

extern "C" void kernel_launch(void* const* d_in, const int* in_sizes, int n_in,
                              void* d_out, int out_size, void* d_ws, size_t ws_size,
                              hipStream_t stream) {
    const float* x  = (const float*)d_in[0];
    const float* lw = (const float*)d_in[1];
    float* out      = (float*)d_out;
    (void)d_ws; (void)ws_size;

    k_fused<<<256, 1024, 0, stream>>>((const f32x4*)x, lw, (f32x4*)out);
}

// Round 5
// 220.879 us; speedup vs baseline: 1.0212x; 1.0212x over previous
//
#include <hip/hip_runtime.h>

#define EPS 1e-5f
#define LOG2E 1.4426950408889634f

typedef float f32x4 __attribute__((ext_vector_type(4)));

// ---------------------------------------------------------------------------
// Fully fused: one 1024-thread block per (b,c) channel (512 blocks total).
// The 256x256 fp32 channel (256 KB) lives entirely in registers:
//   16 waves x 64 lanes x 16 float4 = 16384 float4 = one channel.
// (Unique feasible config: 2 register-resident channels/CU would need the
//  entire 512 KB register file -> no TLP variant exists.)
// Wave w owns the 64x64 patch (pr = w>>2, pc = w&3).
// Phase 1: non-temporal read of the channel (HBM is read exactly once).
// Phase 2: per-wave shfl reduction -> per-patch sum/sumsq in LDS (16 float2).
// Phase 3: threads 0..20 fold stats into exp2-ready coefs (A=-rstd*log2e,
//          B=mu*rstd*log2e) for p=2 (16 patches), p=1 (4 groups), p=0 (full);
//          thread 21 computes the softmaxed level weights. One barrier.
// Phase 4: apply 3 sigmoids from registers, non-temporal store of out.
// Measured 222.2 us total (~55 us kernel) = mixed-stream memory roofline;
// R3 (persistent+prefetch) and R4 (plain stores) variants were neutral/worse.
// ---------------------------------------------------------------------------
__global__ __launch_bounds__(1024) void k_fused(const f32x4* __restrict__ x4,
                                                const float* __restrict__ lw,
                                                f32x4* __restrict__ out4) {
    const int bc   = blockIdx.x;
    const int t    = threadIdx.x;
    const int w    = t >> 6, lane = t & 63;
    const int pr   = w >> 2, pc = w & 3;
    // element (it, lane): row = pr*64 + it*4 + (lane>>4), col4 = pc*16 + (lane&15)
    // -> each wave load = 4 rows x 256 B contiguous segments (fully coalesced)
    const int base = (bc << 14) + (pr * 64 + (lane >> 4)) * 64 + pc * 16 + (lane & 15);

    f32x4 d[16];
#pragma unroll
    for (int it = 0; it < 16; ++it)
        d[it] = __builtin_nontemporal_load(x4 + base + it * 256);

    float s = 0.f, ss = 0.f;
#pragma unroll
    for (int it = 0; it < 16; ++it) {
        const f32x4 v = d[it];
        s  += v[0] + v[1] + v[2] + v[3];
        ss += v[0] * v[0] + v[1] * v[1] + v[2] * v[2] + v[3] * v[3];
    }
#pragma unroll
    for (int off = 32; off > 0; off >>= 1) {
        s  += __shfl_down(s, off, 64);
        ss += __shfl_down(ss, off, 64);
    }

    __shared__ float2 ps[16];      // per-patch (sum, sumsq)
    __shared__ float2 coefs[21];   // 16 x p=2, 4 x p=1, 1 x p=0
    __shared__ float  lws[3];      // softmaxed level weights
    if (lane == 0) ps[w] = make_float2(s, ss);
    __syncthreads();

    if (t < 21) {
        float sum = 0.f, sq = 0.f, n;
        if (t < 16) {                    // p=2: one 64x64 patch
            sum = ps[t].x; sq = ps[t].y; n = 4096.f;
        } else if (t < 20) {             // p=1: 2x2 patch group (128x128)
            const int g = t - 16, gr = g >> 1, gc = g & 1;
            const int b = 8 * gr + 2 * gc;
            sum = ps[b].x + ps[b + 1].x + ps[b + 4].x + ps[b + 5].x;
            sq  = ps[b].y + ps[b + 1].y + ps[b + 4].y + ps[b + 5].y;
            n = 16384.f;
        } else {                         // p=0: full channel
#pragma unroll
            for (int i = 0; i < 16; ++i) { sum += ps[i].x; sq += ps[i].y; }
            n = 65536.f;
        }
        const float mu   = sum / n;
        const float var  = sq / n - mu * mu;
        const float rstd = rsqrtf(var + EPS);
        coefs[t] = make_float2(-rstd * LOG2E, mu * rstd * LOG2E);
    }
    if (t == 21) {
        const float w0 = lw[0], w1 = lw[1], w2 = lw[2];
        const float mx = fmaxf(w0, fmaxf(w1, w2));
        const float a0 = __expf(w0 - mx), a1 = __expf(w1 - mx), a2 = __expf(w2 - mx);
        const float inv = 1.f / (a0 + a1 + a2);
        lws[0] = a0 * inv;   // pairs with p=2 (64x64)
        lws[1] = a1 * inv;   // pairs with p=1 (128x128)
        lws[2] = a2 * inv;   // pairs with p=0 (full)
    }
    __syncthreads();

    // All three coef pairs are wave-uniform.
    const float2 c2 = coefs[w];
    const float2 c1 = coefs[16 + (pr >> 1) * 2 + (pc >> 1)];
    const float2 c0 = coefs[20];
    const float lwA = lws[0], lwB = lws[1], lwC = lws[2];

#pragma unroll
    for (int it = 0; it < 16; ++it) {
        const f32x4 v = d[it];
        f32x4 r;
#pragma unroll
        for (int j = 0; j < 4; ++j) {
            const float xv = v[j];
            const float e2 = __builtin_amdgcn_exp2f(fmaf(xv, c2.x, c2.y));
            const float e1 = __builtin_amdgcn_exp2f(fmaf(xv, c1.x, c1.y));
            const float e0 = __builtin_amdgcn_exp2f(fmaf(xv, c0.x, c0.y));
            const float pA = 1.f + e2, pB = 1.f + e1, pC = 1.f + e0;
            const float mBC = pB * pC, mAB = pA * pB, mAC = pA * pC;
            const float num = fmaf(lwA, mBC, fmaf(lwB, mAC, lwC * mAB));
            const float den = mAB * pC;
            const float t0  = 0.5f * xv;
            r[j] = fmaf(t0 * num, __builtin_amdgcn_rcpf(den), t0);
        }
        __builtin_nontemporal_store(r, out4 + base + it * 256);
    }
}

extern "C" void kernel_launch(void* const* d_in, const int* in_sizes, int n_in,
                              void* d_out, int out_size, void* d_ws, size_t ws_size,
                              hipStream_t stream) {
    const float* x  = (const float*)d_in[0];
    const float* lw = (const float*)d_in[1];
    float* out      = (float*)d_out;
    (void)d_ws; (void)ws_size;

    k_fused<<<512, 1024, 0, stream>>>((const f32x4*)x, lw, (f32x4*)out);
}